// Round 1
// baseline (439.419 us; speedup 1.0000x reference)
//
#include <hip/hip_runtime.h>

// Problem constants (match reference file)
#define D 4096
#define B 8192
#define D4 (D / 4)        // 1024 float4 per row
#define NT 256            // threads per block
#define CHUNKS (D4 / NT)  // 4 float4 per thread per row

// ---------------------------------------------------------------------------
// Kernel 1: compute inverse norms of the two projector columns.
// projector flat layout [2, D, 1] -> proj[0..D) = p_real, proj[D..2D) = p_imag
// ---------------------------------------------------------------------------
__global__ __launch_bounds__(NT) void norms_kernel(const float* __restrict__ proj,
                                                   float* __restrict__ inv_norms) {
    __shared__ float red[4][2];  // 4 waves x {sum_r, sum_i}
    const int tid = threadIdx.x;
    float sr = 0.f, si = 0.f;
    for (int i = tid; i < D; i += NT) {
        float a = proj[i];
        float b = proj[D + i];
        sr += a * a;
        si += b * b;
    }
    // wave (64-lane) reduction
    #pragma unroll
    for (int off = 32; off > 0; off >>= 1) {
        sr += __shfl_down(sr, off, 64);
        si += __shfl_down(si, off, 64);
    }
    const int wave = tid >> 6;
    if ((tid & 63) == 0) {
        red[wave][0] = sr;
        red[wave][1] = si;
    }
    __syncthreads();
    if (tid == 0) {
        float tr = red[0][0] + red[1][0] + red[2][0] + red[3][0];
        float ti = red[0][1] + red[1][1] + red[2][1] + red[3][1];
        inv_norms[0] = 1.0f / sqrtf(tr);
        inv_norms[1] = 1.0f / sqrtf(ti);
    }
}

// ---------------------------------------------------------------------------
// Kernel 2: one block per row b.
//   s_rr = Vr[b]·p_r, s_ri = Vr[b]·p_i, s_ir = Vi[b]·p_r, s_ii = Vi[b]·p_i
//   out_real[b,:] = (s_rr/nr^2) p_r - (s_ii/ni^2) p_i
//   out_imag[b,:] = (s_ri/ni^2) p_i + (s_ir/nr^2) p_r
// ---------------------------------------------------------------------------
__global__ __launch_bounds__(NT) void proj_kernel(const float4* __restrict__ vr,
                                                  const float4* __restrict__ vi,
                                                  const float4* __restrict__ proj,
                                                  const float* __restrict__ inv_norms,
                                                  float4* __restrict__ out) {
    const int b = blockIdx.x;
    const int tid = threadIdx.x;

    const float4* __restrict__ vr_row = vr + (size_t)b * D4;
    const float4* __restrict__ vi_row = vi + (size_t)b * D4;
    const float4* __restrict__ pr = proj;        // first D floats
    const float4* __restrict__ pi = proj + D4;   // next D floats

    float s_rr = 0.f, s_ri = 0.f, s_ir = 0.f, s_ii = 0.f;
    float4 prv[CHUNKS], piv[CHUNKS];

    #pragma unroll
    for (int k = 0; k < CHUNKS; ++k) {
        const int idx = tid + k * NT;
        const float4 a = vr_row[idx];
        const float4 c = vi_row[idx];
        const float4 p = pr[idx];
        const float4 q = pi[idx];
        prv[k] = p;
        piv[k] = q;
        s_rr += a.x * p.x + a.y * p.y + a.z * p.z + a.w * p.w;
        s_ri += a.x * q.x + a.y * q.y + a.z * q.z + a.w * q.w;
        s_ir += c.x * p.x + c.y * p.y + c.z * p.z + c.w * p.w;
        s_ii += c.x * q.x + c.y * q.y + c.z * q.z + c.w * q.w;
    }

    // wave reduction (64 lanes)
    #pragma unroll
    for (int off = 32; off > 0; off >>= 1) {
        s_rr += __shfl_down(s_rr, off, 64);
        s_ri += __shfl_down(s_ri, off, 64);
        s_ir += __shfl_down(s_ir, off, 64);
        s_ii += __shfl_down(s_ii, off, 64);
    }

    __shared__ float red[4][4];  // [wave][value]
    const int wave = tid >> 6;
    if ((tid & 63) == 0) {
        red[wave][0] = s_rr;
        red[wave][1] = s_ri;
        red[wave][2] = s_ir;
        red[wave][3] = s_ii;
    }
    __syncthreads();

    const float S_rr = red[0][0] + red[1][0] + red[2][0] + red[3][0];
    const float S_ri = red[0][1] + red[1][1] + red[2][1] + red[3][1];
    const float S_ir = red[0][2] + red[1][2] + red[2][2] + red[3][2];
    const float S_ii = red[0][3] + red[1][3] + red[2][3] + red[3][3];

    const float inr = inv_norms[0];
    const float ini = inv_norms[1];
    const float inr2 = inr * inr;
    const float ini2 = ini * ini;

    const float alpha = S_rr * inr2;  // coefficient on p_r in out_real
    const float beta  = S_ii * ini2;  // coefficient on p_i in out_real (negated)
    const float gamma = S_ri * ini2;  // coefficient on p_i in out_imag
    const float delta = S_ir * inr2;  // coefficient on p_r in out_imag

    float4* __restrict__ out_r = out + (size_t)b * D4;
    float4* __restrict__ out_i = out + (size_t)B * D4 + (size_t)b * D4;

    #pragma unroll
    for (int k = 0; k < CHUNKS; ++k) {
        const int idx = tid + k * NT;
        const float4 p = prv[k];
        const float4 q = piv[k];
        float4 orr, oii;
        orr.x = alpha * p.x - beta * q.x;
        orr.y = alpha * p.y - beta * q.y;
        orr.z = alpha * p.z - beta * q.z;
        orr.w = alpha * p.w - beta * q.w;
        oii.x = gamma * q.x + delta * p.x;
        oii.y = gamma * q.y + delta * p.y;
        oii.z = gamma * q.z + delta * p.z;
        oii.w = gamma * q.w + delta * p.w;
        out_r[idx] = orr;
        out_i[idx] = oii;
    }
}

extern "C" void kernel_launch(void* const* d_in, const int* in_sizes, int n_in,
                              void* d_out, int out_size, void* d_ws, size_t ws_size,
                              hipStream_t stream) {
    const float* vr   = (const float*)d_in[0];  // v_real_avg  [B, D]
    const float* vi   = (const float*)d_in[1];  // v_imag_avg  [B, D]
    const float* proj = (const float*)d_in[2];  // projector   [2, D, 1]
    float* out        = (float*)d_out;          // [B*D real | B*D imag]
    float* inv_norms  = (float*)d_ws;           // 2 floats of scratch

    norms_kernel<<<1, NT, 0, stream>>>(proj, inv_norms);
    proj_kernel<<<B, NT, 0, stream>>>((const float4*)vr, (const float4*)vi,
                                      (const float4*)proj, inv_norms,
                                      (float4*)out);
}

// Round 2
// 421.397 us; speedup vs baseline: 1.0428x; 1.0428x over previous
//
#include <hip/hip_runtime.h>

// Problem constants (match reference file)
#define D 4096
#define B 8192
#define D4 (D / 4)        // 1024 float4 per row
#define NT 256            // threads per block
#define CHUNKS (D4 / NT)  // 4 float4 per thread per row

// clang extended vector type: nontemporal builtins + scalar*vector arithmetic work on it
typedef float v4 __attribute__((ext_vector_type(4)));

// ---------------------------------------------------------------------------
// Single fused kernel: one block per row b.
// Each block reads the FULL projector (p_r = proj[0:D], p_i = proj[D:2D]),
// so the squared norms can be computed in the same block reduction as the
// four row-dot-products — no separate norms kernel, no workspace.
//
//   S_rr = Vr[b]·p_r, S_ri = Vr[b]·p_i, S_ir = Vi[b]·p_r, S_ii = Vi[b]·p_i
//   P = ||p_r||^2, Q = ||p_i||^2
//   out_real[b,:] = (S_rr/P) p_r - (S_ii/Q) p_i
//   out_imag[b,:] = (S_ri/Q) p_i + (S_ir/P) p_r
//
// V rows and outputs are single-touch -> nontemporal; projector stays in L2.
// ---------------------------------------------------------------------------
__global__ __launch_bounds__(NT) void proj_fused_kernel(const v4* __restrict__ vr,
                                                        const v4* __restrict__ vi,
                                                        const v4* __restrict__ proj,
                                                        v4* __restrict__ out) {
    const int b = blockIdx.x;
    const int tid = threadIdx.x;

    const v4* __restrict__ vr_row = vr + (size_t)b * D4;
    const v4* __restrict__ vi_row = vi + (size_t)b * D4;

    v4 p[CHUNKS], q[CHUNKS], a[CHUNKS], c[CHUNKS];

    // Issue all 16 loads up front (max loads in flight, one vmcnt drain).
    #pragma unroll
    for (int k = 0; k < CHUNKS; ++k) {
        const int idx = tid + k * NT;
        p[k] = proj[idx];        // cached: every block reuses this
        q[k] = proj[D4 + idx];
    }
    #pragma unroll
    for (int k = 0; k < CHUNKS; ++k) {
        const int idx = tid + k * NT;
        a[k] = __builtin_nontemporal_load(&vr_row[idx]);  // single-touch
        c[k] = __builtin_nontemporal_load(&vi_row[idx]);
    }

    float s_pp = 0.f, s_qq = 0.f;
    float s_rr = 0.f, s_ri = 0.f, s_ir = 0.f, s_ii = 0.f;
    #pragma unroll
    for (int k = 0; k < CHUNKS; ++k) {
        #pragma unroll
        for (int j = 0; j < 4; ++j) {
            const float pe = p[k][j];
            const float qe = q[k][j];
            const float ae = a[k][j];
            const float ce = c[k][j];
            s_pp += pe * pe;
            s_qq += qe * qe;
            s_rr += ae * pe;
            s_ri += ae * qe;
            s_ir += ce * pe;
            s_ii += ce * qe;
        }
    }

    // wave (64-lane) butterfly reduction of the 6 partials
    #pragma unroll
    for (int off = 32; off > 0; off >>= 1) {
        s_pp += __shfl_down(s_pp, off, 64);
        s_qq += __shfl_down(s_qq, off, 64);
        s_rr += __shfl_down(s_rr, off, 64);
        s_ri += __shfl_down(s_ri, off, 64);
        s_ir += __shfl_down(s_ir, off, 64);
        s_ii += __shfl_down(s_ii, off, 64);
    }

    __shared__ float red[4][6];  // [wave][value]
    const int wave = tid >> 6;
    if ((tid & 63) == 0) {
        red[wave][0] = s_pp;
        red[wave][1] = s_qq;
        red[wave][2] = s_rr;
        red[wave][3] = s_ri;
        red[wave][4] = s_ir;
        red[wave][5] = s_ii;
    }
    __syncthreads();

    const float P   = red[0][0] + red[1][0] + red[2][0] + red[3][0];
    const float Q   = red[0][1] + red[1][1] + red[2][1] + red[3][1];
    const float Srr = red[0][2] + red[1][2] + red[2][2] + red[3][2];
    const float Sri = red[0][3] + red[1][3] + red[2][3] + red[3][3];
    const float Sir = red[0][4] + red[1][4] + red[2][4] + red[3][4];
    const float Sii = red[0][5] + red[1][5] + red[2][5] + red[3][5];

    const float inr2 = 1.0f / P;   // 1/||p_r||^2
    const float ini2 = 1.0f / Q;   // 1/||p_i||^2

    const float alpha = Srr * inr2;  // p_r coefficient in out_real
    const float beta  = Sii * ini2;  // p_i coefficient in out_real (negated)
    const float gamma = Sri * ini2;  // p_i coefficient in out_imag
    const float delta = Sir * inr2;  // p_r coefficient in out_imag

    v4* __restrict__ out_r = out + (size_t)b * D4;
    v4* __restrict__ out_i = out + (size_t)B * D4 + (size_t)b * D4;

    #pragma unroll
    for (int k = 0; k < CHUNKS; ++k) {
        const int idx = tid + k * NT;
        const v4 orr = alpha * p[k] - beta * q[k];
        const v4 oii = gamma * q[k] + delta * p[k];
        __builtin_nontemporal_store(orr, &out_r[idx]);  // single-touch output
        __builtin_nontemporal_store(oii, &out_i[idx]);
    }
}

extern "C" void kernel_launch(void* const* d_in, const int* in_sizes, int n_in,
                              void* d_out, int out_size, void* d_ws, size_t ws_size,
                              hipStream_t stream) {
    const v4* vr   = (const v4*)d_in[0];  // v_real_avg  [B, D]
    const v4* vi   = (const v4*)d_in[1];  // v_imag_avg  [B, D]
    const v4* proj = (const v4*)d_in[2];  // projector   [2, D, 1]
    v4* out        = (v4*)d_out;          // [B*D real | B*D imag]

    proj_fused_kernel<<<B, NT, 0, stream>>>(vr, vi, proj, out);
}